// Round 12
// baseline (218.009 us; speedup 1.0000x reference)
//
#include <hip/hip_runtime.h>
#include <hip/hip_bf16.h>

#define B_SZ 8192
#define D_SZ 256
#define NTILES 2080   // (8192/128)*(8192/128+1)/2 upper-tri tiles
#define GRID_SIM 1024 // 4 blocks/CU (VGPR-limited), persistent
// rows pre-scaled by sqrt(log2(e)/T): exp2(acc) == exp(sim/T)
#define PRESCALE 4.539816004686735f

typedef __attribute__((ext_vector_type(4))) float f32x4;
typedef __attribute__((ext_vector_type(8))) short s16x8;

// ---- async global->LDS, 16B per lane (wave-uniform LDS base + lane*16) ----
__device__ __forceinline__ void async_copy16(const void* g, void* l) {
    __builtin_amdgcn_global_load_lds(
        (const __attribute__((address_space(1))) unsigned int*)g,
        (__attribute__((address_space(3))) unsigned int*)l,
        16, 0, 0);
}

__device__ __forceinline__ float bf16_as_f32(unsigned u) {
    return __uint_as_float(u << 16);
}

// ---------------- L2-normalize rows, scale, cast to bf16 (+ zero all_sum) --
__global__ __launch_bounds__(256) void norm_kernel(const float* __restrict__ emb,
                                                   ushort* __restrict__ nbf,
                                                   float* __restrict__ all_sum) {
    if (threadIdx.x < 32) all_sum[blockIdx.x * 32 + threadIdx.x] = 0.0f;

    const int wave = threadIdx.x >> 6, lane = threadIdx.x & 63;
    for (int g = blockIdx.x; g < B_SZ / 4; g += 256) {
        const int row = g * 4 + wave;
        const float4 v = ((const float4*)(emb + (size_t)row * D_SZ))[lane];
        float ss = v.x * v.x + v.y * v.y + v.z * v.z + v.w * v.w;
        #pragma unroll
        for (int m = 1; m < 64; m <<= 1) ss += __shfl_xor(ss, m, 64);
        float s = PRESCALE / fmaxf(sqrtf(ss), 1e-12f);
        __hip_bfloat16 b0 = __float2bfloat16(v.x * s);
        __hip_bfloat16 b1 = __float2bfloat16(v.y * s);
        __hip_bfloat16 b2 = __float2bfloat16(v.z * s);
        __hip_bfloat16 b3 = __float2bfloat16(v.w * s);
        ushort4 o;
        o.x = *(ushort*)&b0; o.y = *(ushort*)&b1; o.z = *(ushort*)&b2; o.w = *(ushort*)&b3;
        ((ushort4*)(nbf + (size_t)row * D_SZ))[lane] = o;
    }
}

// ---------------- tile decode + staging helpers ----------------------------
__device__ __forceinline__ void decode_tile(int tb, int& i0, int& j0, bool& diag) {
    int bj = (int)((sqrtf(8.0f * tb + 1.0f) - 1.0f) * 0.5f);
    while ((bj + 1) * (bj + 2) / 2 <= tb) ++bj;
    while (bj * (bj + 1) / 2 > tb) --bj;
    const int bi = tb - bj * (bj + 1) / 2;
    i0 = bi * 128; j0 = bj * 128; diag = (bi == bj);
}

__device__ __forceinline__ void issue_stage(const ushort* __restrict__ N,
                                            int i0, int j0, int k0,
                                            ushort* sA, ushort* sB,
                                            int wave, int r, int c8s) {
    const ushort* gA = N + (size_t)(i0 + wave * 32) * D_SZ + k0;
    const ushort* gB = N + (size_t)(j0 + wave * 32) * D_SZ + k0;
    #pragma unroll
    for (int q = 0; q < 4; ++q) {
        async_copy16(gA + (size_t)(q * 8 + r) * D_SZ + c8s, &sA[(wave * 32 + q * 8) * 64]);
        async_copy16(gB + (size_t)(q * 8 + r) * D_SZ + c8s, &sB[(wave * 32 + q * 8) * 64]);
    }
}

// ---------------- fused sim: pos-pair phase + all_sum tiles ----------------
// Phase 0 (per wave): pos_sum[i] by ballot-scan of ids + direct 64-lane dots
// (positives are ~7/row; removes ALL id logic from the tile epilogue).
// Phase 1: persistent upper-tri 128x128 tiles (r11 structure), BK=64, XOR
// swizzle, register-only epilogue (shuffle row-reduce, no LDS reuse) -> next
// tile's stage-0 prefetches during the epilogue (drain ages ~800 cyc).
__global__ __launch_bounds__(256) void sim_kernel(const ushort* __restrict__ N,
                                                  const int* __restrict__ ids,
                                                  float* __restrict__ all_sum,
                                                  float* __restrict__ pos_sum) {
    __shared__ ushort sA[128 * 64];
    __shared__ ushort sB[128 * 64];

    const int t    = threadIdx.x;
    const int wave = t >> 6, lane = t & 63;
    const int wy   = wave >> 1, wx = wave & 1;
    const int r    = lane >> 3;                     // 0..7 sub-row
    const int c8s  = ((lane & 7) ^ r) * 8;          // swizzled source chunk
    const int myc  = lane & 15;

    // kick off first tile's stage 0 immediately; pos scan hides its latency
    int tb = blockIdx.x;
    int i0, j0; bool diag;
    decode_tile(tb, i0, j0, diag);
    issue_stage(N, i0, j0, 0, sA, sB, wave, r, c8s);

    // ---- phase 0: pos_sum (exclusive writer per row, no init needed) ----
    for (int i = blockIdx.x * 4 + wave; i < B_SZ; i += GRID_SIM * 4) {
        const int idi = ids[i];
        const ushort4 u = *(const ushort4*)&N[(size_t)i * D_SZ + lane * 4];
        const float a0 = bf16_as_f32(u.x), a1 = bf16_as_f32(u.y);
        const float a2 = bf16_as_f32(u.z), a3 = bf16_as_f32(u.w);
        float s = 0.0f;
        for (int base = 0; base < B_SZ; base += 64) {
            unsigned long long m = __ballot(ids[base + lane] == idi);
            if (i >= base && i < base + 64) m &= ~(1ull << (i - base));
            while (m) {
                const int j = base + __ffsll(m) - 1;
                m &= m - 1;
                const ushort4 w = *(const ushort4*)&N[(size_t)j * D_SZ + lane * 4];
                float d = a0 * bf16_as_f32(w.x) + a1 * bf16_as_f32(w.y)
                        + a2 * bf16_as_f32(w.z) + a3 * bf16_as_f32(w.w);
                #pragma unroll
                for (int mm = 1; mm < 64; mm <<= 1) d += __shfl_xor(d, mm, 64);
                s += __builtin_amdgcn_exp2f(d);
            }
        }
        if (lane == 0) pos_sum[i] = s;
    }

    // ---- phase 1: persistent tile loop ----
    while (true) {
        f32x4 acc[4][4];
        #pragma unroll
        for (int mi = 0; mi < 4; ++mi)
            #pragma unroll
            for (int ni = 0; ni < 4; ++ni)
                acc[mi][ni] = (f32x4){0.f, 0.f, 0.f, 0.f};

        for (int kk = 0; kk < 4; ++kk) {
            __syncthreads();   // stage kk ready (per-wave vmcnt drain + barrier)
            #pragma unroll
            for (int ks = 0; ks < 2; ++ks) {
                const int C = ks * 4 + (lane >> 4);     // k-chunk index 0..7
                const int slot = (C ^ (lane & 7)) * 8;  // un-swizzle
                s16x8 af[4], bf[4];
                #pragma unroll
                for (int mi = 0; mi < 4; ++mi)
                    af[mi] = *(const s16x8*)&sA[(wy * 64 + mi * 16 + (lane & 15)) * 64 + slot];
                #pragma unroll
                for (int ni = 0; ni < 4; ++ni)
                    bf[ni] = *(const s16x8*)&sB[(wx * 64 + ni * 16 + (lane & 15)) * 64 + slot];
                #pragma unroll
                for (int mi = 0; mi < 4; ++mi)
                    #pragma unroll
                    for (int ni = 0; ni < 4; ++ni)
                        acc[mi][ni] = __builtin_amdgcn_mfma_f32_16x16x32_bf16(
                            af[mi], bf[ni], acc[mi][ni], 0, 0, 0);
            }
            __syncthreads();   // all reads done -> safe to overwrite staging
            if (kk < 3) issue_stage(N, i0, j0, (kk + 1) * 64, sA, sB, wave, r, c8s);
        }

        // prefetch NEXT tile's stage 0 now; epilogue below hides its latency
        const int ntb = tb + GRID_SIM;
        int ni0 = 0, nj0 = 0; bool ndiag = false;
        if (ntb < NTILES) {
            decode_tile(ntb, ni0, nj0, ndiag);
            issue_stage(N, ni0, nj0, 0, sA, sB, wave, r, c8s);
        }

        // ---- epilogue (registers + shuffles + global atomics only) ----
        // C/D map: col=lane&15, row=(lane>>4)*4+reg
        float cAll[4] = {0.f, 0.f, 0.f, 0.f};
        #pragma unroll
        for (int mi = 0; mi < 4; ++mi) {
            float rAll[4] = {0.f, 0.f, 0.f, 0.f};
            const int rbase = wy * 64 + mi * 16 + (lane >> 4) * 4;
            #pragma unroll
            for (int ni = 0; ni < 4; ++ni) {
                const int cloc = wx * 64 + ni * 16 + myc;
                #pragma unroll
                for (int rg = 0; rg < 4; ++rg) {
                    float e = __builtin_amdgcn_exp2f(acc[mi][ni][rg]);
                    if (diag && (rbase + rg) == cloc) e = 0.0f;   // diagonal
                    rAll[rg] += e; cAll[ni] += e;
                }
            }
            #pragma unroll
            for (int rg = 0; rg < 4; ++rg) {
                #pragma unroll
                for (int mm = 1; mm < 16; mm <<= 1)
                    rAll[rg] += __shfl_xor(rAll[rg], mm, 64);
            }
            if (myc == 0) {
                #pragma unroll
                for (int rg = 0; rg < 4; ++rg)
                    atomicAdd(&all_sum[i0 + rbase + rg], rAll[rg]);
            }
        }
        // column sums -> rows j (off-diagonal tiles only; symmetry)
        if (!diag) {
            #pragma unroll
            for (int ni = 0; ni < 4; ++ni) {
                cAll[ni] += __shfl_xor(cAll[ni], 16, 64);
                cAll[ni] += __shfl_xor(cAll[ni], 32, 64);
            }
            if (lane < 16) {
                #pragma unroll
                for (int ni = 0; ni < 4; ++ni)
                    atomicAdd(&all_sum[j0 + wx * 64 + ni * 16 + lane], cAll[ni]);
            }
        }

        if (ntb >= NTILES) break;
        tb = ntb; i0 = ni0; j0 = nj0; diag = ndiag;
    }
}

// ---------------- final scalar reduce ----------------
__global__ __launch_bounds__(256) void loss_kernel(const float* __restrict__ all_sum,
                                                   const float* __restrict__ pos_sum,
                                                   float* __restrict__ out) {
    float loss = 0.0f, cnt = 0.0f;
    for (int i = threadIdx.x; i < B_SZ; i += 256) {
        float p = pos_sum[i], a = all_sum[i];
        if (p > 0.0f) { loss += logf(a) - logf(p); cnt += 1.0f; }
    }
    #pragma unroll
    for (int m = 1; m < 64; m <<= 1) {
        loss += __shfl_xor(loss, m, 64);
        cnt  += __shfl_xor(cnt, m, 64);
    }
    __shared__ float sl[4], sc[4];
    int wave = threadIdx.x >> 6, lane = threadIdx.x & 63;
    if (lane == 0) { sl[wave] = loss; sc[wave] = cnt; }
    __syncthreads();
    if (threadIdx.x == 0) {
        float L = sl[0] + sl[1] + sl[2] + sl[3];
        float C = sc[0] + sc[1] + sc[2] + sc[3];
        out[0] = L / fmaxf(C, 1.0f);
    }
}

extern "C" void kernel_launch(void* const* d_in, const int* in_sizes, int n_in,
                              void* d_out, int out_size, void* d_ws, size_t ws_size,
                              hipStream_t stream) {
    const float* emb = (const float*)d_in[0];
    const int*   ids = (const int*)d_in[1];
    float*       out = (float*)d_out;

    float*  all_sum = (float*)d_ws;
    float*  pos_sum = all_sum + B_SZ;
    ushort* nbf     = (ushort*)((char*)d_ws + 65536);   // 8192*256 bf16 = 4 MB

    norm_kernel<<<256, 256, 0, stream>>>(emb, nbf, all_sum);
    sim_kernel<<<GRID_SIM, 256, 0, stream>>>(nbf, ids, all_sum, pos_sum);
    loss_kernel<<<1, 256, 0, stream>>>(all_sum, pos_sum, out);
}

// Round 13
// 119.051 us; speedup vs baseline: 1.8312x; 1.8312x over previous
//
#include <hip/hip_runtime.h>
#include <hip/hip_bf16.h>
#include <hip/hip_fp8.h>

#define B_SZ 8192
#define D_SZ 256          // elements per row; fp8 row = 256 B
#define NTILES 2080       // (8192/128)*(8192/128+1)/2 upper-tri tiles
#define GRID_SIM 1024     // persistent
// rows pre-scaled by sqrt(log2(e)/T): exp2(acc) == exp(sim/T)
#define PRESCALE 4.539816004686735f

typedef __attribute__((ext_vector_type(4))) float f32x4;

// ---- async global->LDS, 16B per lane (wave-uniform LDS base + lane*16) ----
__device__ __forceinline__ void async_copy16(const void* g, void* l) {
    __builtin_amdgcn_global_load_lds(
        (const __attribute__((address_space(1))) unsigned int*)g,
        (__attribute__((address_space(3))) unsigned int*)l,
        16, 0, 0);
}

// ---------------- L2-normalize rows, scale, cast to FP8 e4m3 (+ zero sums) -
__global__ __launch_bounds__(256) void norm_kernel(const float* __restrict__ emb,
                                                   unsigned char* __restrict__ nq,
                                                   float* __restrict__ sums) {
    // zero all_sum+pos_sum: 16384 floats over 256 blocks
    sums[blockIdx.x * 64 + (threadIdx.x >> 2)] = 0.0f;

    const int wave = threadIdx.x >> 6, lane = threadIdx.x & 63;
    for (int g = blockIdx.x; g < B_SZ / 4; g += 256) {
        const int row = g * 4 + wave;
        const float4 v = ((const float4*)(emb + (size_t)row * D_SZ))[lane];
        float ss = v.x * v.x + v.y * v.y + v.z * v.z + v.w * v.w;
        #pragma unroll
        for (int m = 1; m < 64; m <<= 1) ss += __shfl_xor(ss, m, 64);
        float s = PRESCALE / fmaxf(sqrtf(ss), 1e-12f);
        __hip_fp8_e4m3 q0(v.x * s), q1(v.y * s), q2(v.z * s), q3(v.w * s);
        uchar4 o;
        o.x = q0.__x; o.y = q1.__x; o.z = q2.__x; o.w = q3.__x;
        ((uchar4*)(nq + (size_t)row * D_SZ))[lane] = o;
    }
}

// ---------------- tile decode + fp8 staging helper -------------------------
__device__ __forceinline__ void decode_tile(int tb, int& i0, int& j0, bool& diag) {
    int bj = (int)((sqrtf(8.0f * tb + 1.0f) - 1.0f) * 0.5f);
    while ((bj + 1) * (bj + 2) / 2 <= tb) ++bj;
    while (bj * (bj + 1) / 2 > tb) --bj;
    const int bi = tb - bj * (bj + 1) / 2;
    i0 = bi * 128; j0 = bj * 128; diag = (bi == bj);
}

// stage 32 rows x 64 B (k-window) per wave per matrix; 2 DMA instrs each.
// 16B-slot XOR swizzle: LDS slot s of row r holds global chunk16 s^((r>>1)&3).
__device__ __forceinline__ void issue_stage_fp8(const unsigned char* __restrict__ N,
                                                int row0, int k0, unsigned char* sDst,
                                                int wave, int lane) {
    const int rowIn = lane >> 2;          // 0..15 within DMA instr
    const int slot  = lane & 3;           // 16B slot 0..3
    #pragma unroll
    for (int h = 0; h < 2; ++h) {
        const int rl  = wave * 32 + h * 16 + rowIn;          // local row 0..127
        const int c16 = slot ^ ((rl >> 1) & 3);              // source chunk16
        async_copy16(N + (size_t)(row0 + rl) * D_SZ + k0 + c16 * 16,
                     sDst + (wave * 32 + h * 16) * 64);
    }
}

// ---------------- fused sim: upper-tri tiles, persistent, FP8 MFMA ---------
// r11 structure, fp8 dtype: 128x128 tile, 4 waves (2x2), BK=64 (bytes),
// mfma_f32_16x16x32_fp8_fp8, LDS staging 16 KB + overlaid 32 KB partials.
__global__ __launch_bounds__(256) void sim_kernel(const unsigned char* __restrict__ N,
                                                  const int* __restrict__ ids,
                                                  float* __restrict__ all_sum,
                                                  float* __restrict__ pos_sum) {
    __shared__ __align__(16) char smem[32768];
    unsigned char* sA = (unsigned char*)smem;           // staging A [128][64] (8 KB)
    unsigned char* sB = (unsigned char*)smem + 8192;    // staging B (8 KB)
    float* rowAllPart = (float*)smem;                   // epilogue [128][32] (16 KB)
    float* rowPosPart = (float*)(smem + 16384);         // epilogue [128][32] (16 KB)

    const int t    = threadIdx.x;
    const int wave = t >> 6, lane = t & 63;
    const int wy   = wave >> 1, wx = wave & 1;
    const int myc  = lane & 15;

    for (int tb = blockIdx.x; tb < NTILES; tb += GRID_SIM) {
        int i0, j0; bool diag;
        decode_tile(tb, i0, j0, diag);

        f32x4 acc[4][4];
        #pragma unroll
        for (int mi = 0; mi < 4; ++mi)
            #pragma unroll
            for (int ni = 0; ni < 4; ++ni)
                acc[mi][ni] = (f32x4){0.f, 0.f, 0.f, 0.f};

        for (int kk = 0; kk < 4; ++kk) {
            issue_stage_fp8(N, i0, kk * 64, sA, wave, lane);
            issue_stage_fp8(N, j0, kk * 64, sB, wave, lane);
            __syncthreads();

            #pragma unroll
            for (int ks = 0; ks < 2; ++ks) {
                const int C = ks * 4 + (lane >> 4);     // 8B chunk 0..7 in window
                long long af[4], bf[4];
                #pragma unroll
                for (int mi = 0; mi < 4; ++mi) {
                    const int rr = wy * 64 + mi * 16 + (lane & 15);
                    const int s16 = (C >> 1) ^ ((rr >> 1) & 3);
                    af[mi] = *(const long long*)&sA[rr * 64 + s16 * 16 + (C & 1) * 8];
                }
                #pragma unroll
                for (int ni = 0; ni < 4; ++ni) {
                    const int rr = wx * 64 + ni * 16 + (lane & 15);
                    const int s16 = (C >> 1) ^ ((rr >> 1) & 3);
                    bf[ni] = *(const long long*)&sB[rr * 64 + s16 * 16 + (C & 1) * 8];
                }
                #pragma unroll
                for (int mi = 0; mi < 4; ++mi)
                    #pragma unroll
                    for (int ni = 0; ni < 4; ++ni)
                        acc[mi][ni] = __builtin_amdgcn_mfma_f32_16x16x32_fp8_fp8(
                            af[mi], bf[ni], acc[mi][ni], 0, 0, 0);
            }
            __syncthreads();   // reads done -> staging region reusable
        }

        // ---- epilogue (r11 logic).  C/D map: col=lane&15, row=(lane>>4)*4+reg
        int idc[4];
        #pragma unroll
        for (int ni = 0; ni < 4; ++ni)
            idc[ni] = ids[j0 + wx * 64 + ni * 16 + myc];

        float cAll[4] = {0.f, 0.f, 0.f, 0.f};
        float cPos[4] = {0.f, 0.f, 0.f, 0.f};

        #pragma unroll
        for (int mi = 0; mi < 4; ++mi) {
            float rAll[4] = {0.f, 0.f, 0.f, 0.f};
            float rPos[4] = {0.f, 0.f, 0.f, 0.f};
            const int rbase = wy * 64 + mi * 16 + (lane >> 4) * 4;
            const int4 idr  = *(const int4*)&ids[i0 + rbase];
            #pragma unroll
            for (int ni = 0; ni < 4; ++ni) {
                const int cloc = wx * 64 + ni * 16 + myc;
                #pragma unroll
                for (int rg = 0; rg < 4; ++rg) {
                    const int lr = rbase + rg;
                    float e = __builtin_amdgcn_exp2f(acc[mi][ni][rg]);
                    if (diag && lr == cloc) e = 0.0f;        // diagonal element
                    rAll[rg] += e; cAll[ni] += e;
                    const int idrv = (rg == 0) ? idr.x : (rg == 1) ? idr.y
                                   : (rg == 2) ? idr.z : idr.w;
                    if (idrv == idc[ni]) { rPos[rg] += e; cPos[ni] += e; }
                }
            }
            #pragma unroll
            for (int rg = 0; rg < 4; ++rg) {
                rowAllPart[(rbase + rg) * 32 + wx * 16 + myc] = rAll[rg];
                rowPosPart[(rbase + rg) * 32 + wx * 16 + myc] = rPos[rg];
            }
        }

        // column sums -> rows j (off-diagonal tiles only; symmetry)
        if (!diag) {
            #pragma unroll
            for (int ni = 0; ni < 4; ++ni) {
                cAll[ni] += __shfl_xor(cAll[ni], 16, 64);
                cAll[ni] += __shfl_xor(cAll[ni], 32, 64);
                cPos[ni] += __shfl_xor(cPos[ni], 16, 64);
                cPos[ni] += __shfl_xor(cPos[ni], 32, 64);
            }
            if (lane < 16) {
                #pragma unroll
                for (int ni = 0; ni < 4; ++ni) {
                    const int gc = j0 + wx * 64 + ni * 16 + lane;
                    atomicAdd(&all_sum[gc], cAll[ni]);
                    atomicAdd(&pos_sum[gc], cPos[ni]);
                }
            }
        }

        __syncthreads();
        // row partial reduce: thread t -> (row = t&127, array = t>>7)
        {
            const int row = t & 127;
            const float* src = (t >= 128) ? rowPosPart : rowAllPart;
            float s = 0.0f;
            #pragma unroll
            for (int k8 = 0; k8 < 8; ++k8) {
                const int chunk = (k8 + (row & 7)) & 7;
                const float4 v = *(const float4*)&src[row * 32 + chunk * 4];
                s += v.x + v.y + v.z + v.w;
            }
            float* dst = (t >= 128) ? pos_sum : all_sum;
            atomicAdd(&dst[i0 + row], s);
        }
        __syncthreads();   // partials consumed before next tile's staging
    }
}

// ---------------- final scalar reduce ----------------
__global__ __launch_bounds__(256) void loss_kernel(const float* __restrict__ all_sum,
                                                   const float* __restrict__ pos_sum,
                                                   float* __restrict__ out) {
    float loss = 0.0f, cnt = 0.0f;
    for (int i = threadIdx.x; i < B_SZ; i += 256) {
        float p = pos_sum[i], a = all_sum[i];
        if (p > 0.0f) { loss += logf(a) - logf(p); cnt += 1.0f; }
    }
    #pragma unroll
    for (int m = 1; m < 64; m <<= 1) {
        loss += __shfl_xor(loss, m, 64);
        cnt  += __shfl_xor(cnt, m, 64);
    }
    __shared__ float sl[4], sc[4];
    int wave = threadIdx.x >> 6, lane = threadIdx.x & 63;
    if (lane == 0) { sl[wave] = loss; sc[wave] = cnt; }
    __syncthreads();
    if (threadIdx.x == 0) {
        float L = sl[0] + sl[1] + sl[2] + sl[3];
        float C = sc[0] + sc[1] + sc[2] + sc[3];
        out[0] = L / fmaxf(C, 1.0f);
    }
}

extern "C" void kernel_launch(void* const* d_in, const int* in_sizes, int n_in,
                              void* d_out, int out_size, void* d_ws, size_t ws_size,
                              hipStream_t stream) {
    const float* emb = (const float*)d_in[0];
    const int*   ids = (const int*)d_in[1];
    float*       out = (float*)d_out;

    float*         all_sum = (float*)d_ws;
    float*         pos_sum = all_sum + B_SZ;
    unsigned char* nq      = (unsigned char*)d_ws + 65536;   // 8192*256 fp8 = 2 MB

    norm_kernel<<<256, 256, 0, stream>>>(emb, nq, all_sum);
    sim_kernel<<<GRID_SIM, 256, 0, stream>>>(nq, ids, all_sum, pos_sum);
    loss_kernel<<<1, 256, 0, stream>>>(all_sum, pos_sum, out);
}